// Round 2
// baseline (1298.843 us; speedup 1.0000x reference)
//
#include <hip/hip_runtime.h>
#include <hip/hip_bf16.h>

// Problem constants (reference: FEAT=1024, N_TAR=60000, N_MSG=45000)
#define FEAT 1024
#define NTAR 60000
#define NMSG 45000
#define MPAD 60032   // 469 * 128
#define BM 128
#define BN 128
#define BK 32
#define KTILES (FEAT / BK)   // 32
#define MTILES (MPAD / BM)   // 469
#define NTILES (FEAT / BN)   // 8
#define NWG (MTILES * NTILES) // 3752 = 8 * 469 (exactly divisible by 8 XCDs)

typedef __bf16 bf16_t;
typedef __attribute__((ext_vector_type(8))) __bf16 bf16x8;
typedef __attribute__((ext_vector_type(4))) __bf16 bf16x4;
typedef __attribute__((ext_vector_type(4))) float f32x4;

// ---------------------------------------------------------------------------
// inv maps: inv_o[t] = m such that o_idx[m] == t, else -1 (memset 0xFF first)
__global__ __launch_bounds__(256) void build_inv_kernel(
    const int* __restrict__ o_idx, const int* __restrict__ s_idx,
    int* __restrict__ inv_o, int* __restrict__ inv_s, int n) {
  int i = blockIdx.x * 256 + threadIdx.x;
  if (i < n) {
    inv_o[o_idx[i]] = i;
    inv_s[s_idx[i]] = i;
  }
}

// ---------------------------------------------------------------------------
// weights f32 -> bf16 (both W1 and W2), 4 elems/thread
__global__ __launch_bounds__(256) void convw_kernel(
    const float* __restrict__ w1, const float* __restrict__ w2,
    bf16_t* __restrict__ W1b, bf16_t* __restrict__ W2b) {
  int i = (blockIdx.x * 256 + threadIdx.x) * 4;
  f32x4 v1 = *(const f32x4*)(w1 + i);
  f32x4 v2 = *(const f32x4*)(w2 + i);
  bf16x4 o1, o2;
#pragma unroll
  for (int j = 0; j < 4; ++j) {
    o1[j] = (bf16_t)v1[j];
    o2[j] = (bf16_t)v2[j];
  }
  *(bf16x4*)(W1b + i) = o1;
  *(bf16x4*)(W2b + i) = o2;
}

// ---------------------------------------------------------------------------
// Fused prep: A1 = bf16(0.5*(gather(msg_o) + gather(msg_s))), A2 = bf16(tar).
// Grid-stride over MPAD*256 f32x4 chunks (2048 blocks x 256 threads).
__global__ __launch_bounds__(256) void prep_kernel(
    const float* __restrict__ msg_o, const float* __restrict__ msg_s,
    const float* __restrict__ tar,
    const int* __restrict__ inv_o, const int* __restrict__ inv_s,
    bf16_t* __restrict__ A1, bf16_t* __restrict__ A2) {
  const int total = MPAD * (FEAT / 4);  // f32x4 chunks
  const int stride = gridDim.x * 256;
#pragma unroll 2
  for (int e = blockIdx.x * 256 + threadIdx.x; e < total; e += stride) {
    const long r = e >> 8;           // row (FEAT/4 = 256 chunks per row)
    const int c = (e & 255) * 4;     // col
    bf16x4 s_out, t_out;
    if (r < NTAR) {
      const int mo = inv_o[r];
      const int ms = inv_s[r];
      f32x4 zed = {0.f, 0.f, 0.f, 0.f};
      f32x4 vo = (mo >= 0) ? *(const f32x4*)(msg_o + (long)mo * FEAT + c) : zed;
      f32x4 vs = (ms >= 0) ? *(const f32x4*)(msg_s + (long)ms * FEAT + c) : zed;
      f32x4 vt = *(const f32x4*)(tar + r * FEAT + c);
#pragma unroll
      for (int j = 0; j < 4; ++j) {
        s_out[j] = (bf16_t)(0.5f * (vo[j] + vs[j]));
        t_out[j] = (bf16_t)vt[j];
      }
    } else {
#pragma unroll
      for (int j = 0; j < 4; ++j) {
        s_out[j] = (bf16_t)0.f;
        t_out[j] = (bf16_t)0.f;
      }
    }
    *(bf16x4*)(A1 + r * FEAT + c) = s_out;
    *(bf16x4*)(A2 + r * FEAT + c) = t_out;
  }
}

// ---------------------------------------------------------------------------
// Single-GEMM kernel, m97 structure: 128x128 tile, BK=32, 4 waves (2x2) of
// 64x64, 16x16x32 MFMA, global_load_lds width-16 staging, chunk-XOR swizzle
// (free 2-way bank alias, verified 0 conflicts in round 1).
// FUSE_S=true : out  = s_f32(gather) + relu(acc + bias)   [G1: A1 @ W1^T]
// FUSE_S=false: out += relu(acc + bias)                   [G2: A2 @ W2^T, RMW]
// Split from the round-1 dual-GEMM: acc drops 128->64 AGPRs so 3 waves/SIMD
// fit (round 1: 216 regs -> 2 waves/SIMD -> 23% occupancy, 15% MfmaUtil).
template <bool FUSE_S>
__global__ __launch_bounds__(256, 3) void gemm_kernel(
    const bf16_t* __restrict__ A, const bf16_t* __restrict__ W,
    const float* __restrict__ bias,
    const float* __restrict__ msg_o, const float* __restrict__ msg_s,
    const int* __restrict__ inv_o, const int* __restrict__ inv_s,
    float* __restrict__ out) {
  __shared__ char lds[32768];  // 2 bufs x (A 8KB + B 8KB)
  const int tid = threadIdx.x;
  const int lane = tid & 63;
  const int wid = tid >> 6;
  const int wm = wid >> 1;  // wave row (0..1)
  const int wn = wid & 1;   // wave col (0..1)

  // Bijective XCD-aware swizzle: NWG = 8*469 exactly. Consecutive works on an
  // XCD share the same mtile (A-panel stays in that XCD's L2).
  const int flat = blockIdx.x;
  const int w = (flat & 7) * (NWG / 8) + (flat >> 3);
  const int mtile = w >> 3;   // NTILES == 8
  const int ntile = w & 7;
  const long row0 = (long)mtile * BM;
  const int col0 = ntile * BN;

  auto stage = [&](int buf, int kt) {
    char* ldsA = lds + buf * 16384;
    char* ldsB = ldsA + 8192;
#pragma unroll
    for (int i = 0; i < 2; ++i) {
      const int idx = i * 256 + tid;  // 512 chunks of 16B = 8KB tile
      const int row = idx >> 2;       // 0..127
      const int gc = (idx & 3) ^ ((row >> 1) & 3);  // inverse-swizzled source
      const bf16_t* srcA = A + (row0 + row) * FEAT + kt * BK + gc * 8;
      __builtin_amdgcn_global_load_lds(
          (const __attribute__((address_space(1))) void*)srcA,
          (__attribute__((address_space(3))) void*)(ldsA + idx * 16), 16, 0, 0);
      const bf16_t* srcW = W + (long)(col0 + row) * FEAT + kt * BK + gc * 8;
      __builtin_amdgcn_global_load_lds(
          (const __attribute__((address_space(1))) void*)srcW,
          (__attribute__((address_space(3))) void*)(ldsB + idx * 16), 16, 0, 0);
    }
  };

  f32x4 acc[4][4] = {};

  auto compute = [&](int buf) {
    const char* ldsA = lds + buf * 16384;
    const char* ldsB = ldsA + 8192;
    const int g = lane >> 4;  // k-chunk (8 bf16 = 16B)
    const int r16 = lane & 15;
    bf16x8 a[4], b[4];
#pragma unroll
    for (int mi = 0; mi < 4; ++mi) {
      const int row = wm * 64 + mi * 16 + r16;
      const int ch = g ^ ((row >> 1) & 3);
      a[mi] = *(const bf16x8*)(ldsA + row * 64 + ch * 16);
    }
#pragma unroll
    for (int ni = 0; ni < 4; ++ni) {
      const int row = wn * 64 + ni * 16 + r16;
      const int ch = g ^ ((row >> 1) & 3);
      b[ni] = *(const bf16x8*)(ldsB + row * 64 + ch * 16);
    }
#pragma unroll
    for (int mi = 0; mi < 4; ++mi)
#pragma unroll
      for (int ni = 0; ni < 4; ++ni)
        acc[mi][ni] =
            __builtin_amdgcn_mfma_f32_16x16x32_bf16(a[mi], b[ni], acc[mi][ni], 0, 0, 0);
  };

  int cur = 0;
  stage(0, 0);
  for (int kt = 0; kt < KTILES; ++kt) {
    __syncthreads();  // drains vmcnt -> buf `cur` staged; prev reads done
    if (kt + 1 < KTILES) stage(cur ^ 1, kt + 1);
    compute(cur);
    cur ^= 1;
  }

  // Epilogue: C/D layout col = lane&15, row = (lane>>4)*4 + reg (m89/m91).
  const int cbase = col0 + wn * 64 + (lane & 15);
  float bv[4];
#pragma unroll
  for (int ni = 0; ni < 4; ++ni) bv[ni] = bias[cbase + ni * 16];
  const long rb = row0 + wm * 64 + ((lane >> 4) * 4);
#pragma unroll
  for (int mi = 0; mi < 4; ++mi) {
#pragma unroll
    for (int r = 0; r < 4; ++r) {
      const long row = rb + mi * 16 + r;
      if (row < NTAR) {
        if (FUSE_S) {
          const int mo = inv_o[row];
          const int ms = inv_s[row];
#pragma unroll
          for (int ni = 0; ni < 4; ++ni) {
            const int col = cbase + ni * 16;
            float s = 0.f;  // exact f32 summarized term via re-gather
            if (mo >= 0) s += 0.5f * msg_o[(long)mo * FEAT + col];
            if (ms >= 0) s += 0.5f * msg_s[(long)ms * FEAT + col];
            out[row * FEAT + col] = s + fmaxf(acc[mi][ni][r] + bv[ni], 0.f);
          }
        } else {
#pragma unroll
          for (int ni = 0; ni < 4; ++ni) {
            const int col = cbase + ni * 16;
            out[row * FEAT + col] += fmaxf(acc[mi][ni][r] + bv[ni], 0.f);
          }
        }
      }
    }
  }
}

// ---------------------------------------------------------------------------
extern "C" void kernel_launch(void* const* d_in, const int* in_sizes, int n_in,
                              void* d_out, int out_size, void* d_ws, size_t ws_size,
                              hipStream_t stream) {
  const float* msg_o = (const float*)d_in[0];
  const float* msg_s = (const float*)d_in[1];
  const int* o_idx = (const int*)d_in[2];
  const int* s_idx = (const int*)d_in[3];
  const float* tar = (const float*)d_in[4];
  const float* w1 = (const float*)d_in[5];
  const float* b1 = (const float*)d_in[6];
  const float* w2 = (const float*)d_in[7];
  const float* b2 = (const float*)d_in[8];
  float* out = (float*)d_out;

  // ws layout (~250.6 MB total)
  char* ws = (char*)d_ws;
  bf16_t* A1 = (bf16_t*)ws;                                      // MPAD x FEAT
  bf16_t* A2 = (bf16_t*)(ws + (size_t)MPAD * FEAT * 2);          // MPAD x FEAT
  bf16_t* W1b = (bf16_t*)(ws + (size_t)MPAD * FEAT * 4);         // FEAT x FEAT
  bf16_t* W2b = (bf16_t*)(ws + (size_t)MPAD * FEAT * 4 + (size_t)FEAT * FEAT * 2);
  int* inv_o = (int*)(ws + (size_t)MPAD * FEAT * 4 + (size_t)FEAT * FEAT * 4);
  int* inv_s = inv_o + MPAD;

  hipMemsetAsync(inv_o, 0xFF, (size_t)MPAD * 2 * sizeof(int), stream);
  build_inv_kernel<<<(NMSG + 255) / 256, 256, 0, stream>>>(o_idx, s_idx, inv_o,
                                                           inv_s, NMSG);
  convw_kernel<<<(FEAT * FEAT / 4) / 256, 256, 0, stream>>>(w1, w2, W1b, W2b);
  prep_kernel<<<2048, 256, 0, stream>>>(msg_o, msg_s, tar, inv_o, inv_s, A1, A2);
  gemm_kernel<true><<<NWG, 256, 0, stream>>>(A1, W1b, b1, msg_o, msg_s, inv_o,
                                             inv_s, out);
  gemm_kernel<false><<<NWG, 256, 0, stream>>>(A2, W2b, b2, msg_o, msg_s, inv_o,
                                              inv_s, out);
}

// Round 3
// 1002.707 us; speedup vs baseline: 1.2953x; 1.2953x over previous
//
#include <hip/hip_runtime.h>
#include <hip/hip_bf16.h>

// Problem constants (reference: FEAT=1024, N_TAR=60000, N_MSG=45000)
#define FEAT 1024
#define NTAR 60000
#define NMSG 45000
#define MPAD 60032    // prep writes this many rows (A1/A2)
#define BM 256
#define BN 256
#define BK 64
#define KT16 (FEAT / BK)        // 16 K-tiles
#define MTILES ((NTAR + BM - 1) / BM)  // 235 (last tile reads pad/garbage rows, outputs masked)
#define NTILES (FEAT / BN)      // 4
#define NWG (MTILES * NTILES)   // 940

typedef __bf16 bf16_t;
typedef __attribute__((ext_vector_type(8))) __bf16 bf16x8;
typedef __attribute__((ext_vector_type(4))) __bf16 bf16x4;
typedef __attribute__((ext_vector_type(4))) float f32x4;

#define BAR() asm volatile("s_barrier" ::: "memory")

// ---------------------------------------------------------------------------
__global__ __launch_bounds__(256) void build_inv_kernel(
    const int* __restrict__ o_idx, const int* __restrict__ s_idx,
    int* __restrict__ inv_o, int* __restrict__ inv_s, int n) {
  int i = blockIdx.x * 256 + threadIdx.x;
  if (i < n) {
    inv_o[o_idx[i]] = i;
    inv_s[s_idx[i]] = i;
  }
}

// ---------------------------------------------------------------------------
__global__ __launch_bounds__(256) void convw_kernel(
    const float* __restrict__ w1, const float* __restrict__ w2,
    bf16_t* __restrict__ W1b, bf16_t* __restrict__ W2b) {
  int i = (blockIdx.x * 256 + threadIdx.x) * 4;
  f32x4 v1 = *(const f32x4*)(w1 + i);
  f32x4 v2 = *(const f32x4*)(w2 + i);
  bf16x4 o1, o2;
#pragma unroll
  for (int j = 0; j < 4; ++j) {
    o1[j] = (bf16_t)v1[j];
    o2[j] = (bf16_t)v2[j];
  }
  *(bf16x4*)(W1b + i) = o1;
  *(bf16x4*)(W2b + i) = o2;
}

// ---------------------------------------------------------------------------
__global__ __launch_bounds__(256) void prep_kernel(
    const float* __restrict__ msg_o, const float* __restrict__ msg_s,
    const float* __restrict__ tar,
    const int* __restrict__ inv_o, const int* __restrict__ inv_s,
    bf16_t* __restrict__ A1, bf16_t* __restrict__ A2) {
  const int total = MPAD * (FEAT / 4);
  const int stride = gridDim.x * 256;
#pragma unroll 2
  for (int e = blockIdx.x * 256 + threadIdx.x; e < total; e += stride) {
    const long r = e >> 8;
    const int c = (e & 255) * 4;
    bf16x4 s_out, t_out;
    if (r < NTAR) {
      const int mo = inv_o[r];
      const int ms = inv_s[r];
      f32x4 zed = {0.f, 0.f, 0.f, 0.f};
      f32x4 vo = (mo >= 0) ? *(const f32x4*)(msg_o + (long)mo * FEAT + c) : zed;
      f32x4 vs = (ms >= 0) ? *(const f32x4*)(msg_s + (long)ms * FEAT + c) : zed;
      f32x4 vt = *(const f32x4*)(tar + r * FEAT + c);
#pragma unroll
      for (int j = 0; j < 4; ++j) {
        s_out[j] = (bf16_t)(0.5f * (vo[j] + vs[j]));
        t_out[j] = (bf16_t)vt[j];
      }
    } else {
#pragma unroll
      for (int j = 0; j < 4; ++j) {
        s_out[j] = (bf16_t)0.f;
        t_out[j] = (bf16_t)0.f;
      }
    }
    *(bf16x4*)(A1 + r * FEAT + c) = s_out;
    *(bf16x4*)(A2 + r * FEAT + c) = t_out;
  }
}

// ---------------------------------------------------------------------------
// 256x256 8-phase GEMM (m201 template, T2+T3+T4+T5).
// 8 waves: wm=wid>>2 (2), wn=wid&3 (4); per-wave out 128x64 = acc[8][4] f32x4.
// LDS 128KB = 2 dbuf x (A 32KB + B 32KB). A stored as 2 halves of 16KB
// (lo = rows (r&127)<64, hi = rest), B as 2 sets (s0 = rows (r&63)<32).
// Half-tiles are staged exactly one-per-phase into regions whose LDS reads
// retired >=1 barrier earlier:
//   phase1: reads A-lo + B-s0 of kt   | stages B-s1 of kt+1 (other buf)
//   phase2: reads B-s1 of kt          | stages A-lo of kt+2 (this buf)
//   phase3: reads A-hi of kt          | stages B-s0 of kt+2
//   phase4: (no ds reads)             | stages A-hi of kt+2; vmcnt(6)
// vmcnt(6) = 3 half-tiles in flight -> kt+1's 4 half-tiles all landed.
// Chunk-XOR swizzle: stored chunk = logical ^ (row&7) (inverse-swizzled
// global source, linear LDS dest -> rule #21 both-sides).
template <bool FUSE_S>
__global__ __launch_bounds__(512, 2) void gemm8_kernel(
    const bf16_t* __restrict__ Ap, const bf16_t* __restrict__ Wp,
    const float* __restrict__ bias, const bf16_t* __restrict__ sS,
    float* __restrict__ out) {
  __shared__ char lds[131072];
  const int tid = threadIdx.x;
  const int lane = tid & 63;
  const int wid = tid >> 6;
  const int wm = wid >> 2;  // 0..1
  const int wn = wid & 3;   // 0..3
  const int g4 = lane >> 4;  // 0..3
  const int r16 = lane & 15;
  const int k7 = r16 & 7;
  const int cb0 = (g4 ^ k7) * 16;        // stored chunk byte, kk=0
  const int cb1 = ((4 + g4) ^ k7) * 16;  // kk=1

  // m204 bijective XCD swizzle, NWG=940: q=117, r=4. 4 consecutive wgids on
  // one XCD share an mtile -> A-panel L2 locality.
  const int orig = blockIdx.x;
  const int xcd = orig & 7, j = orig >> 3;
  const int wgid = (xcd < 4 ? xcd * 118 : 472 + (xcd - 4) * 117) + j;
  const int mtile = wgid >> 2;
  const int ntile = wgid & 3;
  const long row0 = (long)mtile * BM;
  const int col0 = ntile * BN;

  auto stageA = [&](int buf, int h, int kt) {
#pragma unroll
    for (int i = 0; i < 2; ++i) {
      const int idx = i * 512 + tid;
      const int rl = idx >> 3;
      const int row = (rl & 63) + ((rl >> 6) << 7) + (h << 6);
      const int gc = (idx & 7) ^ (rl & 7);
      const bf16_t* src = Ap + (row0 + row) * FEAT + kt * BK + gc * 8;
      __builtin_amdgcn_global_load_lds(
          (const __attribute__((address_space(1))) void*)src,
          (__attribute__((address_space(3))) void*)(lds + buf * 65536 +
                                                    h * 16384 + idx * 16),
          16, 0, 0);
    }
  };
  auto stageB = [&](int buf, int s, int kt) {
#pragma unroll
    for (int i = 0; i < 2; ++i) {
      const int idx = i * 512 + tid;
      const int rl = idx >> 3;
      const int row = (rl & 31) + ((rl >> 5) << 6) + (s << 5);
      const int gc = (idx & 7) ^ (rl & 7);
      const bf16_t* src = Wp + (long)(col0 + row) * FEAT + kt * BK + gc * 8;
      __builtin_amdgcn_global_load_lds(
          (const __attribute__((address_space(1))) void*)src,
          (__attribute__((address_space(3))) void*)(lds + buf * 65536 + 32768 +
                                                    s * 16384 + idx * 16),
          16, 0, 0);
    }
  };

  f32x4 acc[8][4] = {};
  bf16x8 a[4][2], b0[2][2], b1[2][2];

  auto loadA = [&](const char* L, int q) {
#pragma unroll
    for (int m2 = 0; m2 < 4; ++m2) {
      const char* p = L + q * 16384 + (wm * 64 + m2 * 16 + r16) * 128;
      a[m2][0] = *(const bf16x8*)(p + cb0);
      a[m2][1] = *(const bf16x8*)(p + cb1);
    }
  };
  auto loadB = [&](const char* L, int s, bf16x8(&b)[2][2]) {
#pragma unroll
    for (int nn = 0; nn < 2; ++nn) {
      const char* p = L + 32768 + s * 16384 + (wn * 32 + nn * 16 + r16) * 128;
      b[nn][0] = *(const bf16x8*)(p + cb0);
      b[nn][1] = *(const bf16x8*)(p + cb1);
    }
  };
  auto mfma16 = [&](int q, int s, bf16x8(&b)[2][2]) {
    __builtin_amdgcn_s_setprio(1);
#pragma unroll
    for (int m2 = 0; m2 < 4; ++m2)
#pragma unroll
      for (int nn = 0; nn < 2; ++nn)
#pragma unroll
        for (int kk = 0; kk < 2; ++kk)
          acc[q * 4 + m2][s * 2 + nn] = __builtin_amdgcn_mfma_f32_16x16x32_bf16(
              a[m2][kk], b[nn][kk], acc[q * 4 + m2][s * 2 + nn], 0, 0, 0);
    __builtin_amdgcn_s_setprio(0);
  };

  // Prologue: kt0 fully + kt1's {A-lo, B-s0, A-hi} = 7 half-tiles.
  stageA(0, 0, 0); stageA(0, 1, 0); stageB(0, 0, 0); stageB(0, 1, 0);
  stageA(1, 0, 1); stageB(1, 0, 1); stageA(1, 1, 1);
  asm volatile("s_waitcnt vmcnt(6)" ::: "memory");  // kt0's 4 halves landed
  BAR();

  for (int kt = 0; kt < KT16; ++kt) {
    const int buf = kt & 1;
    const char* L = lds + buf * 65536;
    // ---- phase 1: A-lo + B-s0 reads; stage B-s1(kt+1)
    loadA(L, 0);
    loadB(L, 0, b0);
    if (kt + 1 < KT16) stageB(buf ^ 1, 1, kt + 1);
    BAR();
    mfma16(0, 0, b0);
    BAR();
    // ---- phase 2: B-s1 reads; stage A-lo(kt+2)
    loadB(L, 1, b1);
    if (kt + 2 < KT16) stageA(buf, 0, kt + 2);
    BAR();
    mfma16(0, 1, b1);
    BAR();
    // ---- phase 3: A-hi reads; stage B-s0(kt+2)
    loadA(L, 1);
    if (kt + 2 < KT16) stageB(buf, 0, kt + 2);
    BAR();
    mfma16(1, 0, b0);
    BAR();
    // ---- phase 4: stage A-hi(kt+2); counted vmcnt; no ds reads
    if (kt + 2 < KT16) stageA(buf, 1, kt + 2);
    if (kt < KT16 - 2)
      asm volatile("s_waitcnt vmcnt(6)" ::: "memory");  // kt+1 landed, 3 in flight
    else
      asm volatile("s_waitcnt vmcnt(0)" ::: "memory");  // tail drain
    BAR();
    mfma16(1, 1, b1);
    BAR();
  }

  // Epilogue. C/D frag layout: col=lane&15, row=(lane>>4)*4+reg (m89/m91).
  float bv[4];
#pragma unroll
  for (int ni = 0; ni < 4; ++ni) bv[ni] = bias[col0 + wn * 64 + ni * 16 + r16];
#pragma unroll
  for (int mi = 0; mi < 8; ++mi) {
    const int q = mi >> 2, m2 = mi & 3;
#pragma unroll
    for (int r = 0; r < 4; ++r) {
      const long row = row0 + wm * 128 + q * 64 + m2 * 16 + g4 * 4 + r;
      if (row < NTAR) {
#pragma unroll
        for (int ni = 0; ni < 4; ++ni) {
          const int col = col0 + wn * 64 + ni * 16 + r16;
          float v = fmaxf(acc[mi][ni][r] + bv[ni], 0.f);
          if (FUSE_S) {
            v += (float)sS[row * FEAT + col];  // s term from A1 (bf16)
            out[row * FEAT + col] = v;
          } else {
            out[row * FEAT + col] += v;
          }
        }
      }
    }
  }
}

// ---------------------------------------------------------------------------
extern "C" void kernel_launch(void* const* d_in, const int* in_sizes, int n_in,
                              void* d_out, int out_size, void* d_ws, size_t ws_size,
                              hipStream_t stream) {
  const float* msg_o = (const float*)d_in[0];
  const float* msg_s = (const float*)d_in[1];
  const int* o_idx = (const int*)d_in[2];
  const int* s_idx = (const int*)d_in[3];
  const float* tar = (const float*)d_in[4];
  const float* w1 = (const float*)d_in[5];
  const float* b1 = (const float*)d_in[6];
  const float* w2 = (const float*)d_in[7];
  const float* b2 = (const float*)d_in[8];
  float* out = (float*)d_out;

  // ws layout (identical to round 1, ~250.4 MB; GEMM reads <=128 pad rows
  // past A1/A2 into the following regions -> valid memory, outputs masked)
  char* ws = (char*)d_ws;
  bf16_t* A1 = (bf16_t*)ws;
  bf16_t* A2 = (bf16_t*)(ws + (size_t)MPAD * FEAT * 2);
  bf16_t* W1b = (bf16_t*)(ws + (size_t)MPAD * FEAT * 4);
  bf16_t* W2b = (bf16_t*)(ws + (size_t)MPAD * FEAT * 4 + (size_t)FEAT * FEAT * 2);
  int* inv_o = (int*)(ws + (size_t)MPAD * FEAT * 4 + (size_t)FEAT * FEAT * 4);
  int* inv_s = inv_o + MPAD;

  hipMemsetAsync(inv_o, 0xFF, (size_t)MPAD * 2 * sizeof(int), stream);
  build_inv_kernel<<<(NMSG + 255) / 256, 256, 0, stream>>>(o_idx, s_idx, inv_o,
                                                           inv_s, NMSG);
  convw_kernel<<<(FEAT * FEAT / 4) / 256, 256, 0, stream>>>(w1, w2, W1b, W2b);
  prep_kernel<<<2048, 256, 0, stream>>>(msg_o, msg_s, tar, inv_o, inv_s, A1, A2);
  gemm8_kernel<true><<<NWG, 512, 0, stream>>>(A1, W1b, b1, A1, out);
  gemm8_kernel<false><<<NWG, 512, 0, stream>>>(A2, W2b, b2, (const bf16_t*)nullptr, out);
}